// Round 2
// baseline (774.553 us; speedup 1.0000x reference)
//
#include <hip/hip_runtime.h>

#define HDIM 1024
#define MMEM 8192
#define TOPK 2048
#define NROWS 8192
#define LNEPS 1e-5f

typedef unsigned short ushort_t;
typedef __bf16 bf16x8 __attribute__((ext_vector_type(8)));
typedef float f32x4 __attribute__((ext_vector_type(4)));
typedef __attribute__((address_space(1))) const void GVoid;
typedef __attribute__((address_space(3))) void LVoid;

// ---------- helpers ----------
__device__ __forceinline__ ushort_t f2bf(float f) {
    union { float f; unsigned u; } c; c.f = f;
    unsigned r = c.u + 0x7fffu + ((c.u >> 16) & 1u);
    return (ushort_t)(r >> 16);
}
__device__ __forceinline__ float bf2f(ushort_t u) {
    union { unsigned u; float f; } c; c.u = ((unsigned)u) << 16; return c.f;
}
__device__ __forceinline__ float blk_red(float v, int op, float* red) {
    #pragma unroll
    for (int o = 32; o; o >>= 1) {
        float u = __shfl_down(v, o);
        v = op ? fmaxf(v, u) : v + u;
    }
    if ((threadIdx.x & 63) == 0) red[threadIdx.x >> 6] = v;
    __syncthreads();
    float r = op ? fmaxf(fmaxf(red[0], red[1]), fmaxf(red[2], red[3]))
                 : (red[0] + red[1]) + (red[2] + red[3]);
    __syncthreads();
    return r;
}

// ---------- small prep kernels ----------
__global__ __launch_bounds__(256) void sel_prep(const float* __restrict__ sp,
        const float* __restrict__ imp, const float* __restrict__ rec,
        const float* __restrict__ ac, float* __restrict__ sel) {
    __shared__ float red[4];
    float p0 = sp[0], p1 = sp[1], p2 = sp[2];
    float mx = fmaxf(p0, fmaxf(p1, p2));
    float e0 = expf(p0 - mx), e1 = expf(p1 - mx), e2 = expf(p2 - mx);
    float inv = 1.f / (e0 + e1 + e2);
    float w0 = e0 * inv, w1 = e1 * inv, w2 = e2 * inv;
    float m = -1e30f;
    for (int i = threadIdx.x; i < MMEM; i += 256) m = fmaxf(m, ac[i]);
    m = blk_red(m, 1, red);
    float rinv = 1.f / m;
    for (int i = threadIdx.x; i < MMEM; i += 256)
        sel[i] = w0 * imp[i] + w1 * rec[i] + w2 * (ac[i] * rinv);
}

__global__ __launch_bounds__(256) void topk_rank(const float* __restrict__ sel,
                                                 int* __restrict__ idx) {
    __shared__ float s[MMEM];
    for (int i = threadIdx.x; i < MMEM; i += 256) s[i] = sel[i];
    __syncthreads();
    int i = blockIdx.x * 256 + threadIdx.x;
    float si = s[i];
    int cnt = 0;
    #pragma unroll 8
    for (int j = 0; j < MMEM; ++j) {
        float sj = s[j];
        cnt += (sj > si) || (sj == si && j < i);
    }
    if (cnt < TOPK) idx[cnt] = i;
}

__global__ __launch_bounds__(256) void gather_ln(const float* __restrict__ mem_keys,
        const int* __restrict__ idx, const float* __restrict__ g,
        const float* __restrict__ b, ushort_t* __restrict__ out) {
    __shared__ float red[4];
    int src = idx[blockIdx.x] & (MMEM - 1);
    const float* x = mem_keys + (size_t)src * HDIM;
    float4 v = reinterpret_cast<const float4*>(x)[threadIdx.x];
    float s = v.x + v.y + v.z + v.w;
    float ss = v.x*v.x + v.y*v.y + v.z*v.z + v.w*v.w;
    s  = blk_red(s, 0, red);
    ss = blk_red(ss, 0, red);
    float mu = s * (1.f / HDIM);
    float var = ss * (1.f / HDIM) - mu * mu;
    float rstd = rsqrtf(var + LNEPS);
    int c = threadIdx.x * 4;
    ushort4 o;
    o.x = f2bf((v.x - mu) * rstd * g[c+0] + b[c+0]);
    o.y = f2bf((v.y - mu) * rstd * g[c+1] + b[c+1]);
    o.z = f2bf((v.z - mu) * rstd * g[c+2] + b[c+2]);
    o.w = f2bf((v.w - mu) * rstd * g[c+3] + b[c+3]);
    *reinterpret_cast<ushort4*>(out + (size_t)blockIdx.x * HDIM + c) = o;
}

__global__ __launch_bounds__(256) void cvt_bf16(const float* __restrict__ in,
                                                ushort_t* __restrict__ out) {
    size_t i = ((size_t)blockIdx.x * 256 + threadIdx.x) * 4;
    float4 v = *reinterpret_cast<const float4*>(in + i);
    ushort4 o = { f2bf(v.x), f2bf(v.y), f2bf(v.z), f2bf(v.w) };
    *reinterpret_cast<ushort4*>(out + i) = o;
}

__global__ __launch_bounds__(256) void cvt_x_cat(const float* __restrict__ x,
                                                 ushort_t* __restrict__ cat) {
    size_t i = ((size_t)blockIdx.x * 256 + threadIdx.x) * 4;
    size_t row = i >> 10, col = i & 1023;
    float4 v = *reinterpret_cast<const float4*>(x + i);
    ushort4 o = { f2bf(v.x), f2bf(v.y), f2bf(v.z), f2bf(v.w) };
    *reinterpret_cast<ushort4*>(cat + row * 2048 + col) = o;
}

__global__ __launch_bounds__(256) void softmax_rows(ushort_t* __restrict__ sc) {
    __shared__ float red[4];
    ushort_t* p = sc + (size_t)blockIdx.x * 2048 + threadIdx.x * 8;
    ushort4 a = reinterpret_cast<const ushort4*>(p)[0];
    ushort4 bq = reinterpret_cast<const ushort4*>(p)[1];
    float v[8] = { bf2f(a.x), bf2f(a.y), bf2f(a.z), bf2f(a.w),
                   bf2f(bq.x), bf2f(bq.y), bf2f(bq.z), bf2f(bq.w) };
    float mx = v[0];
    #pragma unroll
    for (int j = 1; j < 8; ++j) mx = fmaxf(mx, v[j]);
    mx = blk_red(mx, 1, red);
    float s = 0.f;
    #pragma unroll
    for (int j = 0; j < 8; ++j) { v[j] = expf(v[j] - mx); s += v[j]; }
    s = blk_red(s, 0, red);
    float inv = 1.f / s;
    ushort4 o1 = { f2bf(v[0]*inv), f2bf(v[1]*inv), f2bf(v[2]*inv), f2bf(v[3]*inv) };
    ushort4 o2 = { f2bf(v[4]*inv), f2bf(v[5]*inv), f2bf(v[6]*inv), f2bf(v[7]*inv) };
    reinterpret_cast<ushort4*>(p)[0] = o1;
    reinterpret_cast<ushort4*>(p)[1] = o2;
}

// in-place LN(2048) + exact gelu on bf16 rows; grid = 8192
__global__ __launch_bounds__(256) void ln_gelu(ushort_t* h1,
        const float* __restrict__ g, const float* __restrict__ b) {
    __shared__ float red[4];
    ushort_t* p = h1 + (size_t)blockIdx.x * 2048 + threadIdx.x * 8;
    ushort4 a = reinterpret_cast<const ushort4*>(p)[0];
    ushort4 c = reinterpret_cast<const ushort4*>(p)[1];
    float v[8] = { bf2f(a.x), bf2f(a.y), bf2f(a.z), bf2f(a.w),
                   bf2f(c.x), bf2f(c.y), bf2f(c.z), bf2f(c.w) };
    float s = 0.f, ss = 0.f;
    #pragma unroll
    for (int j = 0; j < 8; ++j) { s += v[j]; ss += v[j]*v[j]; }
    s  = blk_red(s, 0, red);
    ss = blk_red(ss, 0, red);
    float mu = s * (1.f / 2048.f);
    float var = ss * (1.f / 2048.f) - mu * mu;
    float rstd = rsqrtf(var + LNEPS);
    int c0 = threadIdx.x * 8;
    ushort_t o[8];
    #pragma unroll
    for (int j = 0; j < 8; ++j) {
        float xn = (v[j] - mu) * rstd * g[c0 + j] + b[c0 + j];
        float ge = 0.5f * xn * (1.f + erff(xn * 0.70710678118654752f));
        o[j] = f2bf(ge);
    }
    ushort4 o1 = { o[0], o[1], o[2], o[3] };
    ushort4 o2 = { o[4], o[5], o[6], o[7] };
    reinterpret_cast<ushort4*>(p)[0] = o1;
    reinterpret_cast<ushort4*>(p)[1] = o2;
}

// out = LN(x + gate*integ); gate may alias out (read-before-write per thread)
__global__ __launch_bounds__(256) void final_ln(const float* __restrict__ x,
        const float* gate, const ushort_t* __restrict__ integ,
        const float* __restrict__ g, const float* __restrict__ b,
        float* out) {
    __shared__ float red[4];
    size_t base = (size_t)blockIdx.x * HDIM + threadIdx.x * 4;
    float4 xv = *reinterpret_cast<const float4*>(x + base);
    float4 gv = *reinterpret_cast<const float4*>(gate + base);
    ushort4 iv = *reinterpret_cast<const ushort4*>(integ + base);
    float v[4] = { xv.x + gv.x*bf2f(iv.x), xv.y + gv.y*bf2f(iv.y),
                   xv.z + gv.z*bf2f(iv.z), xv.w + gv.w*bf2f(iv.w) };
    float s = v[0]+v[1]+v[2]+v[3];
    float ss = v[0]*v[0]+v[1]*v[1]+v[2]*v[2]+v[3]*v[3];
    s  = blk_red(s, 0, red);
    ss = blk_red(ss, 0, red);
    float mu = s * (1.f / HDIM);
    float var = ss * (1.f / HDIM) - mu * mu;
    float rstd = rsqrtf(var + LNEPS);
    int c = threadIdx.x * 4;
    float4 o;
    o.x = (v[0] - mu) * rstd * g[c+0] + b[c+0];
    o.y = (v[1] - mu) * rstd * g[c+1] + b[c+1];
    o.z = (v[2] - mu) * rstd * g[c+2] + b[c+2];
    o.w = (v[3] - mu) * rstd * g[c+3] + b[c+3];
    *reinterpret_cast<float4*>(out + base) = o;
}

// ---------- MFMA GEMM: C = scale*(A . B^T) + bias ----------
// EPI: 0=f32, 1=bf16, 2=sigmoid->f32 ; BIAS: 0=none, 1=per-col, 2=per-row
// zg = zbase + blockIdx.z; z1 = zg/z2n; z2 = zg%z2n; zz = blockIdx.z (local)
template<int EPI, int BIAS>
__global__ __launch_bounds__(256, 2)
void gemm_bt(const ushort_t* __restrict__ A, const ushort_t* __restrict__ B,
             const float* __restrict__ bias, void* __restrict__ Cv,
             int K, int lda, int ldb, int ldc,
             long long sA1, long long sA2, long long sAz,
             long long sB1, long long sB2, long long sBz,
             long long sC1, long long sC2, long long sCz,
             int z2n, int zbase, float scale)
{
    __shared__ __align__(16) ushort_t As[8192];   // 128 x 64
    __shared__ __align__(16) ushort_t Bs[8192];   // 128 x 64
    const int zz = blockIdx.z;
    const int zg = zz + zbase;
    const int z1 = zg / z2n, z2 = zg - z1 * z2n;
    A += (size_t)(z1 * sA1 + z2 * sA2 + zz * sAz);
    B += (size_t)(z1 * sB1 + z2 * sB2 + zz * sBz);
    const size_t cOff = (size_t)(z1 * sC1 + z2 * sC2 + zz * sCz);
    const int m0 = blockIdx.y * 128, n0 = blockIdx.x * 128;
    const int tid = threadIdx.x;
    const int w = tid >> 6, l = tid & 63;
    const int wm = w >> 1, wn = w & 1;

    f32x4 acc[4][4] = {};

    // staging: chunk c = 8 rows; lane l -> row c*8 + l/8, 16B at XOR-swizzled col.
    const int srow = l >> 3;
    const int scol = ((l & 7) ^ srow) << 3;   // elements

    for (int k0 = 0; k0 < K; k0 += 64) {
        #pragma unroll
        for (int i = 0; i < 4; ++i) {
            const int c = i * 4 + w;
            const int row = c * 8 + srow;
            const ushort_t* ga = A + (size_t)(m0 + row) * lda + (k0 + scol);
            const ushort_t* gb = B + (size_t)(n0 + row) * ldb + (k0 + scol);
            __builtin_amdgcn_global_load_lds((GVoid*)ga, (LVoid*)(As + c * 512), 16, 0, 0);
            __builtin_amdgcn_global_load_lds((GVoid*)gb, (LVoid*)(Bs + c * 512), 16, 0, 0);
        }
        __syncthreads();
        #pragma unroll
        for (int kk = 0; kk < 2; ++kk) {
            bf16x8 af[4], bfv[4];
            #pragma unroll
            for (int m = 0; m < 4; ++m) {
                const int row = wm * 64 + m * 16 + (l & 15);
                const int cb = ((kk * 64) + ((l >> 4) * 16)) ^ ((row & 7) << 4);
                af[m] = *reinterpret_cast<const bf16x8*>(
                    reinterpret_cast<const char*>(As) + row * 128 + cb);
            }
            #pragma unroll
            for (int n = 0; n < 4; ++n) {
                const int row = wn * 64 + n * 16 + (l & 15);
                const int cb = ((kk * 64) + ((l >> 4) * 16)) ^ ((row & 7) << 4);
                bfv[n] = *reinterpret_cast<const bf16x8*>(
                    reinterpret_cast<const char*>(Bs) + row * 128 + cb);
            }
            #pragma unroll
            for (int m = 0; m < 4; ++m)
                #pragma unroll
                for (int n = 0; n < 4; ++n)
                    acc[m][n] = __builtin_amdgcn_mfma_f32_16x16x32_bf16(
                        af[m], bfv[n], acc[m][n], 0, 0, 0);
        }
        __syncthreads();
    }

    #pragma unroll
    for (int m = 0; m < 4; ++m) {
        const int grow = m0 + wm * 64 + m * 16 + ((l >> 4) << 2);
        #pragma unroll
        for (int n = 0; n < 4; ++n) {
            const int gcol = n0 + wn * 64 + n * 16 + (l & 15);
            float bc = (BIAS == 1) ? bias[gcol] : 0.f;
            #pragma unroll
            for (int j = 0; j < 4; ++j) {
                float v = acc[m][n][j] * scale;
                if (BIAS == 1) v += bc;
                if (BIAS == 2) v += bias[grow + j];
                if (EPI == 2) v = 1.f / (1.f + expf(-v));
                const size_t off = cOff + (size_t)(grow + j) * ldc + gcol;
                if (EPI == 1) ((ushort_t*)Cv)[off] = f2bf(v);
                else          ((float*)Cv)[off]    = v;
            }
        }
    }
}

// ---------- host ----------
extern "C" void kernel_launch(void* const* d_in, const int* in_sizes, int n_in,
                              void* d_out, int out_size, void* d_ws, size_t ws_size,
                              hipStream_t stream) {
    const float* x          = (const float*)d_in[0];
    const float* mem_keys   = (const float*)d_in[1];
    const float* importance = (const float*)d_in[2];
    const float* recency    = (const float*)d_in[3];
    const float* access_cnt = (const float*)d_in[4];
    const float* Wq         = (const float*)d_in[5];
    const float* bq         = (const float*)d_in[6];
    const float* in_w       = (const float*)d_in[7];
    const float* in_b       = (const float*)d_in[8];
    const float* out_w      = (const float*)d_in[9];
    const float* out_b      = (const float*)d_in[10];
    const float* gate_w     = (const float*)d_in[11];
    const float* gate_b     = (const float*)d_in[12];
    const float* int_w1     = (const float*)d_in[13];
    const float* int_b1     = (const float*)d_in[14];
    const float* int_ln_g   = (const float*)d_in[15];
    const float* int_ln_b   = (const float*)d_in[16];
    const float* int_w2     = (const float*)d_in[17];
    const float* int_b2     = (const float*)d_in[18];
    const float* ln1_g      = (const float*)d_in[19];
    const float* ln1_b      = (const float*)d_in[20];
    const float* ln2_g      = (const float*)d_in[21];
    const float* ln2_b      = (const float*)d_in[22];
    const float* sel_params = (const float*)d_in[23];

    char* ws = (char*)d_ws;
    size_t off = 0;
    auto alloc = [&](size_t bytes) -> char* {
        char* p = ws + off;
        off = (off + bytes + 255) & ~(size_t)255;
        return p;
    };

    float*    sel      = (float*)alloc(MMEM * 4);
    int*      idx      = (int*)alloc(TOPK * 4);
    ushort_t* wq_bf    = (ushort_t*)alloc((size_t)1048576 * 2);   // 2 MB
    ushort_t* inw_bf   = (ushort_t*)alloc((size_t)3145728 * 2);   // 6 MB
    ushort_t* outw_bf  = (ushort_t*)alloc((size_t)1048576 * 2);   // 2 MB
    ushort_t* gatew_bf = (ushort_t*)alloc((size_t)2097152 * 2);   // 4 MB
    ushort_t* intw1_bf = (ushort_t*)alloc((size_t)4194304 * 2);   // 8 MB
    ushort_t* intw2_bf = (ushort_t*)alloc((size_t)2097152 * 2);   // 4 MB
    ushort_t* mem_n    = (ushort_t*)alloc((size_t)TOPK * HDIM * 2);   // 4 MB
    ushort_t* Kbuf     = (ushort_t*)alloc((size_t)TOPK * HDIM * 2);   // 4 MB
    ushort_t* Vt       = (ushort_t*)alloc((size_t)HDIM * TOPK * 2);   // 4 MB
    ushort_t* cat      = (ushort_t*)alloc((size_t)NROWS * 2048 * 2);  // 32 MB
    ushort_t* qQ       = (ushort_t*)alloc((size_t)NROWS * 2048 * 2);  // 32 MB
    ushort_t* qbuf     = qQ;                            // 8192x1024 bf16
    ushort_t* Qbuf     = qQ + (size_t)NROWS * HDIM;     // 8192x1024 bf16
    ushort_t* h1       = qQ;                            // 8192x2048 bf16 (q/Q dead)
    ushort_t* ctx      = (ushort_t*)alloc((size_t)NROWS * HDIM * 2);  // 16 MB
    ushort_t* integ    = ctx;                           // bf16, ctx dead by then
    float*    gatev    = (float*)d_out;                 // 32 MB, overwritten at end

    // adaptive score-chunk size: NC z-slices of 16, each 8 MB
    int NC = 8;
    while (NC > 1 && off + (size_t)NC * 8388608 > ws_size) NC >>= 1;
    ushort_t* scores = (ushort_t*)alloc((size_t)NC * 8388608);

    // weight conversions (f32 -> bf16)
    cvt_bf16<<<1024, 256, 0, stream>>>(Wq, wq_bf);
    cvt_bf16<<<3072, 256, 0, stream>>>(in_w, inw_bf);
    cvt_bf16<<<1024, 256, 0, stream>>>(out_w, outw_bf);
    cvt_bf16<<<2048, 256, 0, stream>>>(gate_w, gatew_bf);
    cvt_bf16<<<4096, 256, 0, stream>>>(int_w1, intw1_bf);
    cvt_bf16<<<2048, 256, 0, stream>>>(int_w2, intw2_bf);
    cvt_x_cat<<<8192, 256, 0, stream>>>(x, cat);

    // selection + gather + LN1
    sel_prep<<<1, 256, 0, stream>>>(sel_params, importance, recency, access_cnt, sel);
    topk_rank<<<MMEM/256, 256, 0, stream>>>(sel, idx);
    gather_ln<<<TOPK, 256, 0, stream>>>(mem_keys, idx, ln1_g, ln1_b, mem_n);

    // q = x @ Wq^T + bq
    gemm_bt<1,1><<<dim3(8,64,1), 256, 0, stream>>>(cat, wq_bf, bq, qbuf,
        1024, 2048, 1024, 1024, 0,0,0, 0,0,0, 0,0,0, 1, 0, 1.f);
    // Q = q @ wq^T + bqi
    gemm_bt<1,1><<<dim3(8,64,1), 256, 0, stream>>>(qbuf, inw_bf, in_b, Qbuf,
        1024, 1024, 1024, 1024, 0,0,0, 0,0,0, 0,0,0, 1, 0, 1.f);
    // K = mem_n @ wk^T + bki
    gemm_bt<1,1><<<dim3(8,16,1), 256, 0, stream>>>(mem_n, inw_bf + 1048576, in_b + 1024,
        Kbuf, 1024, 1024, 1024, 1024, 0,0,0, 0,0,0, 0,0,0, 1, 0, 1.f);
    // Vt = wv @ mem_n^T + bvi(per-row)   (1024 x 2048)
    gemm_bt<1,2><<<dim3(16,8,1), 256, 0, stream>>>(inw_bf + 2097152, mem_n, in_b + 2048,
        Vt, 1024, 1024, 1024, 2048, 0,0,0, 0,0,0, 0,0,0, 1, 0, 1.f);

    // attention in chunks of NC (z = b*4+h over 16)
    for (int c0 = 0; c0 < 16; c0 += NC) {
        gemm_bt<1,0><<<dim3(16,16,NC), 256, 0, stream>>>(Qbuf, Kbuf, nullptr, scores,
            256, 1024, 1024, 2048,
            /*sA1*/2097152, /*sA2*/256, /*sAz*/0,
            /*sB1*/0, /*sB2*/256, /*sBz*/0,
            /*sC1*/0, /*sC2*/0, /*sCz*/4194304, 4, c0, 0.0625f);
        softmax_rows<<<NC * 2048, 256, 0, stream>>>(scores);
        gemm_bt<1,0><<<dim3(2,16,NC), 256, 0, stream>>>(scores, Vt, nullptr, ctx,
            2048, 2048, 2048, 1024,
            /*sA1*/0, /*sA2*/0, /*sAz*/4194304,
            /*sB1*/0, /*sB2*/524288, /*sBz*/0,
            /*sC1*/2097152, /*sC2*/256, /*sCz*/0, 4, c0, 1.f);
    }

    // attn_out -> cat[:, 1024:]
    gemm_bt<1,1><<<dim3(8,64,1), 256, 0, stream>>>(ctx, outw_bf, out_b,
        (void*)(cat + 1024), 1024, 1024, 1024, 2048, 0,0,0, 0,0,0, 0,0,0, 1, 0, 1.f);

    // gate = sigmoid(cat @ gate_w^T + gate_b) -> f32 in d_out
    gemm_bt<2,1><<<dim3(8,64,1), 256, 0, stream>>>(cat, gatew_bf, gate_b, gatev,
        2048, 2048, 2048, 1024, 0,0,0, 0,0,0, 0,0,0, 1, 0, 1.f);
    // h1 = cat @ int_w1^T + int_b1 (bf16, over dead q/Q)
    gemm_bt<1,1><<<dim3(16,64,1), 256, 0, stream>>>(cat, intw1_bf, int_b1, h1,
        2048, 2048, 2048, 2048, 0,0,0, 0,0,0, 0,0,0, 1, 0, 1.f);
    // h1 = gelu(LN(h1)) in place
    ln_gelu<<<NROWS, 256, 0, stream>>>(h1, int_ln_g, int_ln_b);
    // integ = h1 @ int_w2^T + int_b2 (bf16, over dead ctx)
    gemm_bt<1,1><<<dim3(8,64,1), 256, 0, stream>>>(h1, intw2_bf, int_b2, integ,
        2048, 2048, 2048, 1024, 0,0,0, 0,0,0, 0,0,0, 1, 0, 1.f);
    // out = LN(x + gate*integ)
    final_ln<<<NROWS, 256, 0, stream>>>(x, gatev, integ, ln2_g, ln2_b, (float*)d_out);
}

// Round 3
// 631.567 us; speedup vs baseline: 1.2264x; 1.2264x over previous
//
#include <hip/hip_runtime.h>

#define HDIM 1024
#define MMEM 8192
#define TOPK 2048
#define NROWS 8192
#define LNEPS 1e-5f

typedef unsigned short ushort_t;
typedef __bf16 bf16x8 __attribute__((ext_vector_type(8)));
typedef float f32x4 __attribute__((ext_vector_type(4)));
typedef __attribute__((address_space(1))) const void GVoid;
typedef __attribute__((address_space(3))) void LVoid;

// ---------- helpers ----------
__device__ __forceinline__ ushort_t f2bf(float f) {
    union { float f; unsigned u; } c; c.f = f;
    unsigned r = c.u + 0x7fffu + ((c.u >> 16) & 1u);
    return (ushort_t)(r >> 16);
}
__device__ __forceinline__ float bf2f(ushort_t u) {
    union { unsigned u; float f; } c; c.u = ((unsigned)u) << 16; return c.f;
}
__device__ __forceinline__ float blk_red(float v, int op, float* red) {
    #pragma unroll
    for (int o = 32; o; o >>= 1) {
        float u = __shfl_down(v, o);
        v = op ? fmaxf(v, u) : v + u;
    }
    if ((threadIdx.x & 63) == 0) red[threadIdx.x >> 6] = v;
    __syncthreads();
    float r = op ? fmaxf(fmaxf(red[0], red[1]), fmaxf(red[2], red[3]))
                 : (red[0] + red[1]) + (red[2] + red[3]);
    __syncthreads();
    return r;
}

// ---------- small prep kernels ----------
__global__ __launch_bounds__(256) void sel_prep(const float* __restrict__ sp,
        const float* __restrict__ imp, const float* __restrict__ rec,
        const float* __restrict__ ac, float* __restrict__ sel) {
    __shared__ float red[4];
    float p0 = sp[0], p1 = sp[1], p2 = sp[2];
    float mx = fmaxf(p0, fmaxf(p1, p2));
    float e0 = expf(p0 - mx), e1 = expf(p1 - mx), e2 = expf(p2 - mx);
    float inv = 1.f / (e0 + e1 + e2);
    float w0 = e0 * inv, w1 = e1 * inv, w2 = e2 * inv;
    float m = -1e30f;
    for (int i = threadIdx.x; i < MMEM; i += 256) m = fmaxf(m, ac[i]);
    m = blk_red(m, 1, red);
    float rinv = 1.f / m;
    for (int i = threadIdx.x; i < MMEM; i += 256)
        sel[i] = w0 * imp[i] + w1 * rec[i] + w2 * (ac[i] * rinv);
}

// rank-based exact top-k: grid 256 blocks x 32 i's; 8 j-chunks per i.
__global__ __launch_bounds__(256) void topk_rank(const float* __restrict__ sel,
                                                 int* __restrict__ idx) {
    __shared__ float s[MMEM];        // 32 KB
    __shared__ int pc[256];
    for (int t = threadIdx.x; t < MMEM / 4; t += 256)
        reinterpret_cast<float4*>(s)[t] = reinterpret_cast<const float4*>(sel)[t];
    __syncthreads();
    const int li = threadIdx.x & 31;
    const int jc = threadIdx.x >> 5;
    const int i  = blockIdx.x * 32 + li;
    const float si = s[i];
    int cnt = 0;
    const float4* sv = reinterpret_cast<const float4*>(s) + jc * 256;
    #pragma unroll 4
    for (int t = 0; t < 256; ++t) {
        float4 v = sv[t];
        int j0 = jc * 1024 + t * 4;
        cnt += (v.x > si) || (v.x == si && (j0 + 0) < i);
        cnt += (v.y > si) || (v.y == si && (j0 + 1) < i);
        cnt += (v.z > si) || (v.z == si && (j0 + 2) < i);
        cnt += (v.w > si) || (v.w == si && (j0 + 3) < i);
    }
    pc[threadIdx.x] = cnt;
    __syncthreads();
    if (threadIdx.x < 32) {
        int r = 0;
        #pragma unroll
        for (int c = 0; c < 8; ++c) r += pc[c * 32 + threadIdx.x];
        if (r < TOPK) idx[r] = blockIdx.x * 32 + threadIdx.x;
    }
}

__global__ __launch_bounds__(256) void gather_ln(const float* __restrict__ mem_keys,
        const int* __restrict__ idx, const float* __restrict__ g,
        const float* __restrict__ b, ushort_t* __restrict__ out) {
    __shared__ float red[4];
    int src = idx[blockIdx.x] & (MMEM - 1);
    const float* x = mem_keys + (size_t)src * HDIM;
    float4 v = reinterpret_cast<const float4*>(x)[threadIdx.x];
    float s = v.x + v.y + v.z + v.w;
    float ss = v.x*v.x + v.y*v.y + v.z*v.z + v.w*v.w;
    s  = blk_red(s, 0, red);
    ss = blk_red(ss, 0, red);
    float mu = s * (1.f / HDIM);
    float var = ss * (1.f / HDIM) - mu * mu;
    float rstd = rsqrtf(var + LNEPS);
    int c = threadIdx.x * 4;
    ushort4 o;
    o.x = f2bf((v.x - mu) * rstd * g[c+0] + b[c+0]);
    o.y = f2bf((v.y - mu) * rstd * g[c+1] + b[c+1]);
    o.z = f2bf((v.z - mu) * rstd * g[c+2] + b[c+2]);
    o.w = f2bf((v.w - mu) * rstd * g[c+3] + b[c+3]);
    *reinterpret_cast<ushort4*>(out + (size_t)blockIdx.x * HDIM + c) = o;
}

__global__ __launch_bounds__(256) void cvt_bf16(const float* __restrict__ in,
                                                ushort_t* __restrict__ out) {
    size_t i = ((size_t)blockIdx.x * 256 + threadIdx.x) * 4;
    float4 v = *reinterpret_cast<const float4*>(in + i);
    ushort4 o = { f2bf(v.x), f2bf(v.y), f2bf(v.z), f2bf(v.w) };
    *reinterpret_cast<ushort4*>(out + i) = o;
}

__global__ __launch_bounds__(256) void cvt_x_cat(const float* __restrict__ x,
                                                 ushort_t* __restrict__ cat) {
    size_t i = ((size_t)blockIdx.x * 256 + threadIdx.x) * 4;
    size_t row = i >> 10, col = i & 1023;
    float4 v = *reinterpret_cast<const float4*>(x + i);
    ushort4 o = { f2bf(v.x), f2bf(v.y), f2bf(v.z), f2bf(v.w) };
    *reinterpret_cast<ushort4*>(cat + row * 2048 + col) = o;
}

__global__ __launch_bounds__(256) void softmax_rows(ushort_t* __restrict__ sc) {
    __shared__ float red[4];
    ushort_t* p = sc + (size_t)blockIdx.x * 2048 + threadIdx.x * 8;
    ushort4 a = reinterpret_cast<const ushort4*>(p)[0];
    ushort4 bq = reinterpret_cast<const ushort4*>(p)[1];
    float v[8] = { bf2f(a.x), bf2f(a.y), bf2f(a.z), bf2f(a.w),
                   bf2f(bq.x), bf2f(bq.y), bf2f(bq.z), bf2f(bq.w) };
    float mx = v[0];
    #pragma unroll
    for (int j = 1; j < 8; ++j) mx = fmaxf(mx, v[j]);
    mx = blk_red(mx, 1, red);
    float s = 0.f;
    #pragma unroll
    for (int j = 0; j < 8; ++j) { v[j] = expf(v[j] - mx); s += v[j]; }
    s = blk_red(s, 0, red);
    float inv = 1.f / s;
    ushort4 o1 = { f2bf(v[0]*inv), f2bf(v[1]*inv), f2bf(v[2]*inv), f2bf(v[3]*inv) };
    ushort4 o2 = { f2bf(v[4]*inv), f2bf(v[5]*inv), f2bf(v[6]*inv), f2bf(v[7]*inv) };
    reinterpret_cast<ushort4*>(p)[0] = o1;
    reinterpret_cast<ushort4*>(p)[1] = o2;
}

// in-place LN(2048) + exact gelu on bf16 rows; grid = 8192
__global__ __launch_bounds__(256) void ln_gelu(ushort_t* h1,
        const float* __restrict__ g, const float* __restrict__ b) {
    __shared__ float red[4];
    ushort_t* p = h1 + (size_t)blockIdx.x * 2048 + threadIdx.x * 8;
    ushort4 a = reinterpret_cast<const ushort4*>(p)[0];
    ushort4 c = reinterpret_cast<const ushort4*>(p)[1];
    float v[8] = { bf2f(a.x), bf2f(a.y), bf2f(a.z), bf2f(a.w),
                   bf2f(c.x), bf2f(c.y), bf2f(c.z), bf2f(c.w) };
    float s = 0.f, ss = 0.f;
    #pragma unroll
    for (int j = 0; j < 8; ++j) { s += v[j]; ss += v[j]*v[j]; }
    s  = blk_red(s, 0, red);
    ss = blk_red(ss, 0, red);
    float mu = s * (1.f / 2048.f);
    float var = ss * (1.f / 2048.f) - mu * mu;
    float rstd = rsqrtf(var + LNEPS);
    int c0 = threadIdx.x * 8;
    ushort_t o[8];
    #pragma unroll
    for (int j = 0; j < 8; ++j) {
        float xn = (v[j] - mu) * rstd * g[c0 + j] + b[c0 + j];
        float ge = 0.5f * xn * (1.f + erff(xn * 0.70710678118654752f));
        o[j] = f2bf(ge);
    }
    ushort4 o1 = { o[0], o[1], o[2], o[3] };
    ushort4 o2 = { o[4], o[5], o[6], o[7] };
    reinterpret_cast<ushort4*>(p)[0] = o1;
    reinterpret_cast<ushort4*>(p)[1] = o2;
}

// out = LN(x + gate*integ); gate may alias out (read-before-write per thread)
__global__ __launch_bounds__(256) void final_ln(const float* __restrict__ x,
        const float* gate, const ushort_t* __restrict__ integ,
        const float* __restrict__ g, const float* __restrict__ b,
        float* out) {
    __shared__ float red[4];
    size_t base = (size_t)blockIdx.x * HDIM + threadIdx.x * 4;
    float4 xv = *reinterpret_cast<const float4*>(x + base);
    float4 gv = *reinterpret_cast<const float4*>(gate + base);
    ushort4 iv = *reinterpret_cast<const ushort4*>(integ + base);
    float v[4] = { xv.x + gv.x*bf2f(iv.x), xv.y + gv.y*bf2f(iv.y),
                   xv.z + gv.z*bf2f(iv.z), xv.w + gv.w*bf2f(iv.w) };
    float s = v[0]+v[1]+v[2]+v[3];
    float ss = v[0]*v[0]+v[1]*v[1]+v[2]*v[2]+v[3]*v[3];
    s  = blk_red(s, 0, red);
    ss = blk_red(ss, 0, red);
    float mu = s * (1.f / HDIM);
    float var = ss * (1.f / HDIM) - mu * mu;
    float rstd = rsqrtf(var + LNEPS);
    int c = threadIdx.x * 4;
    float4 o;
    o.x = (v[0] - mu) * rstd * g[c+0] + b[c+0];
    o.y = (v[1] - mu) * rstd * g[c+1] + b[c+1];
    o.z = (v[2] - mu) * rstd * g[c+2] + b[c+2];
    o.w = (v[3] - mu) * rstd * g[c+3] + b[c+3];
    *reinterpret_cast<float4*>(out + base) = o;
}

// ---------- MFMA GEMM: C = scale*(A . B^T) + bias ----------
// EPI: 0=f32, 1=bf16, 2=sigmoid->f32 ; BIAS: 0=none, 1=per-col, 2=per-row
template<int EPI, int BIAS>
__global__ __launch_bounds__(256, 2)
void gemm_bt(const ushort_t* __restrict__ A, const ushort_t* __restrict__ B,
             const float* __restrict__ bias, void* __restrict__ Cv,
             int K, int lda, int ldb, int ldc,
             long long sA1, long long sA2, long long sAz,
             long long sB1, long long sB2, long long sBz,
             long long sC1, long long sC2, long long sCz,
             int z2n, int zbase, float scale)
{
    __shared__ __align__(16) ushort_t As[8192];   // 128 x 64
    __shared__ __align__(16) ushort_t Bs[8192];   // 128 x 64
    const int zz = blockIdx.z;
    const int zg = zz + zbase;
    const int z1 = zg / z2n, z2 = zg - z1 * z2n;
    A += (size_t)(z1 * sA1 + z2 * sA2 + zz * sAz);
    B += (size_t)(z1 * sB1 + z2 * sB2 + zz * sBz);
    const size_t cOff = (size_t)(z1 * sC1 + z2 * sC2 + zz * sCz);
    const int m0 = blockIdx.y * 128, n0 = blockIdx.x * 128;
    const int tid = threadIdx.x;
    const int w = tid >> 6, l = tid & 63;
    const int wm = w >> 1, wn = w & 1;

    f32x4 acc[4][4] = {};

    const int srow = l >> 3;
    const int scol = ((l & 7) ^ srow) << 3;   // elements

    for (int k0 = 0; k0 < K; k0 += 64) {
        #pragma unroll
        for (int i = 0; i < 4; ++i) {
            const int c = i * 4 + w;
            const int row = c * 8 + srow;
            const ushort_t* ga = A + (size_t)(m0 + row) * lda + (k0 + scol);
            const ushort_t* gb = B + (size_t)(n0 + row) * ldb + (k0 + scol);
            __builtin_amdgcn_global_load_lds((GVoid*)ga, (LVoid*)(As + c * 512), 16, 0, 0);
            __builtin_amdgcn_global_load_lds((GVoid*)gb, (LVoid*)(Bs + c * 512), 16, 0, 0);
        }
        __syncthreads();
        #pragma unroll
        for (int kk = 0; kk < 2; ++kk) {
            bf16x8 af[4], bfv[4];
            #pragma unroll
            for (int m = 0; m < 4; ++m) {
                const int row = wm * 64 + m * 16 + (l & 15);
                const int cb = ((kk * 64) + ((l >> 4) * 16)) ^ ((row & 7) << 4);
                af[m] = *reinterpret_cast<const bf16x8*>(
                    reinterpret_cast<const char*>(As) + row * 128 + cb);
            }
            #pragma unroll
            for (int n = 0; n < 4; ++n) {
                const int row = wn * 64 + n * 16 + (l & 15);
                const int cb = ((kk * 64) + ((l >> 4) * 16)) ^ ((row & 7) << 4);
                bfv[n] = *reinterpret_cast<const bf16x8*>(
                    reinterpret_cast<const char*>(Bs) + row * 128 + cb);
            }
            #pragma unroll
            for (int m = 0; m < 4; ++m)
                #pragma unroll
                for (int n = 0; n < 4; ++n)
                    acc[m][n] = __builtin_amdgcn_mfma_f32_16x16x32_bf16(
                        af[m], bfv[n], acc[m][n], 0, 0, 0);
        }
        __syncthreads();
    }

    #pragma unroll
    for (int m = 0; m < 4; ++m) {
        const int grow = m0 + wm * 64 + m * 16 + ((l >> 4) << 2);
        #pragma unroll
        for (int n = 0; n < 4; ++n) {
            const int gcol = n0 + wn * 64 + n * 16 + (l & 15);
            float bc = (BIAS == 1) ? bias[gcol] : 0.f;
            #pragma unroll
            for (int j = 0; j < 4; ++j) {
                float v = acc[m][n][j] * scale;
                if (BIAS == 1) v += bc;
                if (BIAS == 2) v += bias[grow + j];
                if (EPI == 2) v = 1.f / (1.f + expf(-v));
                const size_t off = cOff + (size_t)(grow + j) * ldc + gcol;
                if (EPI == 1) ((ushort_t*)Cv)[off] = f2bf(v);
                else          ((float*)Cv)[off]    = v;
            }
        }
    }
}

// ---------- host ----------
extern "C" void kernel_launch(void* const* d_in, const int* in_sizes, int n_in,
                              void* d_out, int out_size, void* d_ws, size_t ws_size,
                              hipStream_t stream) {
    const float* x          = (const float*)d_in[0];
    const float* mem_keys   = (const float*)d_in[1];
    const float* importance = (const float*)d_in[2];
    const float* recency    = (const float*)d_in[3];
    const float* access_cnt = (const float*)d_in[4];
    const float* Wq         = (const float*)d_in[5];
    const float* bq         = (const float*)d_in[6];
    const float* in_w       = (const float*)d_in[7];
    const float* in_b       = (const float*)d_in[8];
    const float* out_w      = (const float*)d_in[9];
    const float* out_b      = (const float*)d_in[10];
    const float* gate_w     = (const float*)d_in[11];
    const float* gate_b     = (const float*)d_in[12];
    const float* int_w1     = (const float*)d_in[13];
    const float* int_b1     = (const float*)d_in[14];
    const float* int_ln_g   = (const float*)d_in[15];
    const float* int_ln_b   = (const float*)d_in[16];
    const float* int_w2     = (const float*)d_in[17];
    const float* int_b2     = (const float*)d_in[18];
    const float* ln1_g      = (const float*)d_in[19];
    const float* ln1_b      = (const float*)d_in[20];
    const float* ln2_g      = (const float*)d_in[21];
    const float* ln2_b      = (const float*)d_in[22];
    const float* sel_params = (const float*)d_in[23];

    char* ws = (char*)d_ws;
    size_t off = 0;
    auto alloc = [&](size_t bytes) -> char* {
        char* p = ws + off;
        off = (off + bytes + 255) & ~(size_t)255;
        return p;
    };

    float*    sel      = (float*)alloc(MMEM * 4);
    int*      idx      = (int*)alloc(TOPK * 4);
    ushort_t* wq_bf    = (ushort_t*)alloc((size_t)1048576 * 2);   // 2 MB
    ushort_t* inw_bf   = (ushort_t*)alloc((size_t)3145728 * 2);   // 6 MB
    ushort_t* outw_bf  = (ushort_t*)alloc((size_t)1048576 * 2);   // 2 MB
    ushort_t* gatew_bf = (ushort_t*)alloc((size_t)2097152 * 2);   // 4 MB
    ushort_t* intw1_bf = (ushort_t*)alloc((size_t)4194304 * 2);   // 8 MB
    ushort_t* intw2_bf = (ushort_t*)alloc((size_t)2097152 * 2);   // 4 MB
    ushort_t* mem_n    = (ushort_t*)alloc((size_t)TOPK * HDIM * 2);   // 4 MB
    ushort_t* Kbuf     = (ushort_t*)alloc((size_t)TOPK * HDIM * 2);   // 4 MB
    ushort_t* Vt       = (ushort_t*)alloc((size_t)HDIM * TOPK * 2);   // 4 MB
    ushort_t* cat      = (ushort_t*)alloc((size_t)NROWS * 2048 * 2);  // 32 MB
    ushort_t* qQ       = (ushort_t*)alloc((size_t)NROWS * 2048 * 2);  // 32 MB
    ushort_t* qbuf     = qQ;                            // 8192x1024 bf16
    ushort_t* Qbuf     = qQ + (size_t)NROWS * HDIM;     // 8192x1024 bf16
    ushort_t* h1       = qQ;                            // 8192x2048 bf16 (q/Q dead)
    ushort_t* ctx      = (ushort_t*)alloc((size_t)NROWS * HDIM * 2);  // 16 MB
    ushort_t* integ    = ctx;                           // bf16, ctx dead by then
    float*    gatev    = (float*)d_out;                 // 32 MB, overwritten at end

    int NC = 8;
    while (NC > 1 && off + (size_t)NC * 8388608 > ws_size) NC >>= 1;
    ushort_t* scores = (ushort_t*)alloc((size_t)NC * 8388608);

    cvt_bf16<<<1024, 256, 0, stream>>>(Wq, wq_bf);
    cvt_bf16<<<3072, 256, 0, stream>>>(in_w, inw_bf);
    cvt_bf16<<<1024, 256, 0, stream>>>(out_w, outw_bf);
    cvt_bf16<<<2048, 256, 0, stream>>>(gate_w, gatew_bf);
    cvt_bf16<<<4096, 256, 0, stream>>>(int_w1, intw1_bf);
    cvt_bf16<<<2048, 256, 0, stream>>>(int_w2, intw2_bf);
    cvt_x_cat<<<8192, 256, 0, stream>>>(x, cat);

    sel_prep<<<1, 256, 0, stream>>>(sel_params, importance, recency, access_cnt, sel);
    topk_rank<<<MMEM/32, 256, 0, stream>>>(sel, idx);
    gather_ln<<<TOPK, 256, 0, stream>>>(mem_keys, idx, ln1_g, ln1_b, mem_n);

    // q = x @ Wq^T + bq
    gemm_bt<1,1><<<dim3(8,64,1), 256, 0, stream>>>(cat, wq_bf, bq, qbuf,
        1024, 2048, 1024, 1024, 0,0,0, 0,0,0, 0,0,0, 1, 0, 1.f);
    // Q = q @ wq^T + bqi
    gemm_bt<1,1><<<dim3(8,64,1), 256, 0, stream>>>(qbuf, inw_bf, in_b, Qbuf,
        1024, 1024, 1024, 1024, 0,0,0, 0,0,0, 0,0,0, 1, 0, 1.f);
    // K = mem_n @ wk^T + bki
    gemm_bt<1,1><<<dim3(8,16,1), 256, 0, stream>>>(mem_n, inw_bf + 1048576, in_b + 1024,
        Kbuf, 1024, 1024, 1024, 1024, 0,0,0, 0,0,0, 0,0,0, 1, 0, 1.f);
    // Vt = wv @ mem_n^T + bvi(per-row)   (1024 x 2048)
    gemm_bt<1,2><<<dim3(16,8,1), 256, 0, stream>>>(inw_bf + 2097152, mem_n, in_b + 2048,
        Vt, 1024, 1024, 1024, 2048, 0,0,0, 0,0,0, 0,0,0, 1, 0, 1.f);

    for (int c0 = 0; c0 < 16; c0 += NC) {
        gemm_bt<1,0><<<dim3(16,16,NC), 256, 0, stream>>>(Qbuf, Kbuf, nullptr, scores,
            256, 1024, 1024, 2048,
            2097152, 256, 0,  0, 256, 0,  0, 0, 4194304, 4, c0, 0.0625f);
        softmax_rows<<<NC * 2048, 256, 0, stream>>>(scores);
        gemm_bt<1,0><<<dim3(2,16,NC), 256, 0, stream>>>(scores, Vt, nullptr, ctx,
            2048, 2048, 2048, 1024,
            0, 0, 4194304,  0, 524288, 0,  2097152, 256, 0, 4, c0, 1.f);
    }

    // attn_out -> cat[:, 1024:]
    gemm_bt<1,1><<<dim3(8,64,1), 256, 0, stream>>>(ctx, outw_bf, out_b,
        (void*)(cat + 1024), 1024, 1024, 1024, 2048, 0,0,0, 0,0,0, 0,0,0, 1, 0, 1.f);

    // gate = sigmoid(cat @ gate_w^T + gate_b) -> f32 in d_out
    gemm_bt<2,1><<<dim3(8,64,1), 256, 0, stream>>>(cat, gatew_bf, gate_b, gatev,
        2048, 2048, 2048, 1024, 0,0,0, 0,0,0, 0,0,0, 1, 0, 1.f);
    // h1 = cat @ int_w1^T + int_b1 (bf16, over dead q/Q)
    gemm_bt<1,1><<<dim3(16,64,1), 256, 0, stream>>>(cat, intw1_bf, int_b1, h1,
        2048, 2048, 2048, 2048, 0,0,0, 0,0,0, 0,0,0, 1, 0, 1.f);
    ln_gelu<<<NROWS, 256, 0, stream>>>(h1, int_ln_g, int_ln_b);
    // integ = h1 @ int_w2^T + int_b2 (bf16, over dead ctx)
    gemm_bt<1,1><<<dim3(8,64,1), 256, 0, stream>>>(h1, intw2_bf, int_b2, integ,
        2048, 2048, 2048, 1024, 0,0,0, 0,0,0, 0,0,0, 1, 0, 1.f);
    final_ln<<<NROWS, 256, 0, stream>>>(x, gatev, integ, ln2_g, ln2_b, (float*)d_out);
}